// Round 8
// baseline (239.635 us; speedup 1.0000x reference)
//
#include <hip/hip_runtime.h>
#include <hip/hip_bf16.h>

// IDST (DST-III, x2) as y = x @ W, W[n][k] = 2*a_n*sin(pi*(n+1)*(2k+1)/(2N)).
// R8: R7's register read-ahead-1 with the aliasing bug fixed: af now has two
// banks af[mh][m][kk], so the read-ahead of next tile's af-mh0 (P4/P8) no
// longer clobbers af-mh1 used by that phase's q11 MFMA. Phase p issues the
// ds_reads for phase p+1's MFMA (full barrier window of LDS latency cover).
// Staging schedule + vmcnt(4)@P3/P7 unchanged from R7 (ledger re-verified).

#define MDIM 4096
#define NDIM 4096
#define KDIM 4096
#define NKT  (KDIM / 64)

using f32x4  = __attribute__((ext_vector_type(4))) float;
using bf16x8 = __attribute__((ext_vector_type(8))) short;

__device__ inline unsigned short f2bf(float f) {
    union { float f; unsigned int u; } v; v.f = f;
    unsigned int r = (v.u + 0x7fffu + ((v.u >> 16) & 1u)) >> 16; // RNE
    return (unsigned short)r;
}

__global__ __launch_bounds__(256) void cvt_x_bf16(const float* __restrict__ x,
                                                  unsigned short* __restrict__ o) {
    int idx = blockIdx.x * 256 + threadIdx.x;
    const float4* xin = (const float4*)x;
    float4 a = xin[2 * idx];
    float4 b = xin[2 * idx + 1];
    union { unsigned short u[8]; uint4 v; } r;
    r.u[0] = f2bf(a.x); r.u[1] = f2bf(a.y); r.u[2] = f2bf(a.z); r.u[3] = f2bf(a.w);
    r.u[4] = f2bf(b.x); r.u[5] = f2bf(b.y); r.u[6] = f2bf(b.z); r.u[7] = f2bf(b.w);
    ((uint4*)o)[idx] = r.v;
}

__global__ __launch_bounds__(256) void gen_Wt(unsigned short* __restrict__ Wt) {
    int idx = blockIdx.x * 256 + threadIdx.x;
    int k  = idx >> 9;
    int n0 = (idx & 511) * 8;
    unsigned int tk = 2u * (unsigned)k + 1u;
    union { unsigned short u[8]; uint4 v; } r;
#pragma unroll
    for (int t = 0; t < 8; ++t) {
        unsigned int n = (unsigned)(n0 + t);
        unsigned int m = ((n + 1u) * tk) & 16383u;
        float ang = (float)m * 3.8349519697e-4f;   // pi/8192
        float s = __sinf(ang);
        float scale = (n == (unsigned)(KDIM - 1)) ? 1.0f : 2.0f;
        r.u[t] = f2bf(s * scale);
    }
    ((uint4*)Wt)[idx] = r.v;
}

// Stage one quarter-tile (64 rows as 16 x 8-row groups), 2 gload_lds/thread.
//   Ae: groups {0-7,16-23}     rows {0-63,128-191}
//   Ao: +8                     rows {64-127,192-255}
//   Be: {0-3,8-11,16-19,24-27} rows {0-31,64-95,128-159,192-223}
//   Bo: +4
// Linear LDS dest per 8-row group; global source slot pre-swizzled (^row&7).
template <int SEL>
__device__ __forceinline__ void stage_part(const unsigned short* __restrict__ G,
                                           int growbase, int kbase,
                                           unsigned short* lds, int w, int l) {
#pragma unroll
    for (int j = 0; j < 2; ++j) {
        int gi = j * 8 + w;
        int base8;
        if constexpr (SEL == 0)      base8 = (gi & 7) + (gi >> 3) * 16;
        else if constexpr (SEL == 1) base8 = (gi & 7) + (gi >> 3) * 16 + 8;
        else if constexpr (SEL == 2) base8 = (gi & 3) + (gi >> 2) * 8;
        else                         base8 = (gi & 3) + (gi >> 2) * 8 + 4;
        int row  = base8 * 8 + (l >> 3);
        int scol = ((l & 7) ^ (l >> 3)) * 8;
        __builtin_amdgcn_global_load_lds(
            (const __attribute__((address_space(1))) unsigned int*)
                (G + (size_t)(growbase + row) * KDIM + kbase + scol),
            (__attribute__((address_space(3))) unsigned int*)(lds + base8 * 512),
            16, 0, 0);
    }
}
#define ST_AE 0
#define ST_AO 1
#define ST_BE 2
#define ST_BO 3

template <int MH, int NH>
__device__ __forceinline__ void do_mfma(f32x4 (&acc)[8][4], bf16x8 (&af)[2][4][2],
                                        bf16x8 (&bf)[2][2][2]) {
#pragma unroll
    for (int m = 0; m < 4; ++m)
#pragma unroll
        for (int n = 0; n < 2; ++n)
#pragma unroll
            for (int kk = 0; kk < 2; ++kk)
                acc[MH * 4 + m][NH * 2 + n] =
                    __builtin_amdgcn_mfma_f32_16x16x32_bf16(
                        af[MH][m][kk], bf[NH][n][kk], acc[MH * 4 + m][NH * 2 + n],
                        0, 0, 0);
}

__global__ __launch_bounds__(512, 2) void gemm_bt(const unsigned short* __restrict__ A,
                                                  const unsigned short* __restrict__ Bt,
                                                  float* __restrict__ C) {
    __shared__ unsigned short LDS[4 * 256 * 64];   // 128 KiB
    unsigned short* const as0 = LDS;
    unsigned short* const as1 = LDS + 16384;
    unsigned short* const bs0 = LDS + 32768;
    unsigned short* const bs1 = LDS + 49152;

    const int tid = threadIdx.x;
    const int w = tid >> 6, l = tid & 63;
    const int wr = w >> 2, wc = w & 3;
    const int brow = blockIdx.y * 256, bcol = blockIdx.x * 256;

    const int rl = l & 15, g = l >> 4;
    const int aoff  = (wr * 128 + rl) * 64;
    const int boff  = (wc * 64 + rl) * 64;
    const int k0off = ((g)     ^ (rl & 7)) * 8;
    const int k1off = ((4 + g) ^ (rl & 7)) * 8;

    f32x4 acc[8][4];
#pragma unroll
    for (int m = 0; m < 8; ++m)
#pragma unroll
        for (int n = 0; n < 4; ++n) acc[m][n] = (f32x4){0.f, 0.f, 0.f, 0.f};

    bf16x8 af[2][4][2];   // af[mh][m][kk] — two banks, no cross-phase alias
    bf16x8 bf[2][2][2];   // bf[nh][n][kk]

    // Frag lifetimes (MFMA order q00,q01,q10,q11; reads one phase ahead):
    //   af[0]: load P8'/pre (tile t), use P1,P2; reload P4 (tile t+1)
    //   bf[0]: load P8'/pre,          use P1,P3; reload P4
    //   bf[1]: load P1, use P2,P4; reload P5
    //   af[1]: load P2, use P3,P4; reload P6
    // Per-phase: written regs disjoint from MFMA operands in every phase.

#define RD_A(pa, mh)                                                          \
    _Pragma("unroll") for (int m = 0; m < 4; ++m) {                           \
        af[mh][m][0] = *(const bf16x8*)((pa) + aoff + ((mh) * 64 + m * 16) * 64 + k0off); \
        af[mh][m][1] = *(const bf16x8*)((pa) + aoff + ((mh) * 64 + m * 16) * 64 + k1off); \
    }
#define RD_B(pb, nh)                                                          \
    _Pragma("unroll") for (int n = 0; n < 2; ++n) {                           \
        bf[nh][n][0] = *(const bf16x8*)((pb) + boff + ((nh) * 32 + n * 16) * 64 + k0off); \
        bf[nh][n][1] = *(const bf16x8*)((pb) + boff + ((nh) * 32 + n * 16) * 64 + k1off); \
    }

#define KB(t) ((((t) & (NKT - 1))) * 64)

#define PH_END(MH, NH)                                                        \
    __builtin_amdgcn_s_setprio(1);                                            \
    do_mfma<MH, NH>(acc, af, bf);                                             \
    __builtin_amdgcn_s_setprio(0);                                            \
    asm volatile("" ::: "memory");                                            \
    __builtin_amdgcn_s_barrier();

#define PH_END_VM(MH, NH)                                                     \
    __builtin_amdgcn_s_setprio(1);                                            \
    do_mfma<MH, NH>(acc, af, bf);                                             \
    __builtin_amdgcn_s_setprio(0);                                            \
    asm volatile("s_waitcnt vmcnt(4)" ::: "memory");                          \
    __builtin_amdgcn_s_barrier();

    // Prologue: T0 (4 parts, buf0) + T1 (Ae,Be,Bo, buf1); drain T0, keep
    // T1's 3 parts (6 loads) in flight. Then preload P1's frags (tile 0).
    stage_part<ST_AE>(A,  brow, 0,  as0, w, l);
    stage_part<ST_AO>(A,  brow, 0,  as0, w, l);
    stage_part<ST_BE>(Bt, bcol, 0,  bs0, w, l);
    stage_part<ST_BO>(Bt, bcol, 0,  bs0, w, l);
    stage_part<ST_AE>(A,  brow, 64, as1, w, l);
    stage_part<ST_BE>(Bt, bcol, 64, bs1, w, l);
    stage_part<ST_BO>(Bt, bcol, 64, bs1, w, l);
    asm volatile("s_waitcnt vmcnt(6)" ::: "memory");
    __builtin_amdgcn_s_barrier();
    RD_A(as0, 0); RD_B(bs0, 0);   // frags for P1's q(0,0)

    for (int it = 0; it < NKT / 2; ++it) {
        const int t2 = 2 * it;

        // ---- tile t2 (buf0) ----
        // P1: MFMA q00(af0,bf0); read bf[1] (tile t2); stage (t2+1).Ao
        RD_B(bs0, 1);
        stage_part<ST_AO>(A, brow, KB(t2 + 1), as1, w, l);
        PH_END(0, 0)
        // P2: MFMA q01(af0,bf1); read af[1] (tile t2); stage (t2+2).Ae
        RD_A(as0, 1);
        stage_part<ST_AE>(A, brow, KB(t2 + 2), as0, w, l);
        PH_END(0, 1)
        // P3: MFMA q10(af1,bf0); stage (t2+2).Be;
        //     vmcnt(4) drains P6',P7',P8',P1 = all of t2+1 (buf1)
        stage_part<ST_BE>(Bt, bcol, KB(t2 + 2), bs0, w, l);
        PH_END_VM(1, 0)
        // P4: MFMA q11(af1,bf1); read af[0],bf[0] from buf1 (tile t2+1);
        //     stage (t2+2).Bo
        RD_A(as1, 0); RD_B(bs1, 0);
        stage_part<ST_BO>(Bt, bcol, KB(t2 + 2), bs0, w, l);
        PH_END(1, 1)

        // ---- tile t2+1 (buf1) ----
        // P5: MFMA q00(af0,bf0); read bf[1] (buf1); stage (t2+2).Ao
        RD_B(bs1, 1);
        stage_part<ST_AO>(A, brow, KB(t2 + 2), as0, w, l);
        PH_END(0, 0)
        // P6: MFMA q01(af0,bf1); read af[1] (buf1); stage (t2+3).Ae
        RD_A(as1, 1);
        stage_part<ST_AE>(A, brow, KB(t2 + 3), as1, w, l);
        PH_END(0, 1)
        // P7: MFMA q10(af1,bf0); stage (t2+3).Be;
        //     vmcnt(4) drains P2,P3,P4,P5 = all of t2+2 (buf0)
        stage_part<ST_BE>(Bt, bcol, KB(t2 + 3), bs1, w, l);
        PH_END_VM(1, 0)
        // P8: MFMA q11(af1,bf1); read af[0],bf[0] from buf0 (t2+2);
        //     stage (t2+3).Bo
        RD_A(as0, 0); RD_B(bs0, 0);
        stage_part<ST_BO>(Bt, bcol, KB(t2 + 3), bs1, w, l);
        PH_END(1, 1)
    }

    asm volatile("s_waitcnt vmcnt(0) lgkmcnt(0)" ::: "memory");

    // C/D layout: col = lane&15, row = (lane>>4)*4 + reg
#pragma unroll
    for (int m = 0; m < 8; ++m) {
        int r0 = brow + wr * 128 + m * 16 + (l >> 4) * 4;
#pragma unroll
        for (int n = 0; n < 4; ++n) {
            int c0 = bcol + wc * 64 + n * 16 + rl;
#pragma unroll
            for (int r = 0; r < 4; ++r)
                C[(size_t)(r0 + r) * NDIM + c0] = acc[m][n][r];
        }
    }
#undef RD_A
#undef RD_B
#undef KB
#undef PH_END
#undef PH_END_VM
}

extern "C" void kernel_launch(void* const* d_in, const int* in_sizes, int n_in,
                              void* d_out, int out_size, void* d_ws, size_t ws_size,
                              hipStream_t stream) {
    const float* x = (const float*)d_in[0];
    float* out = (float*)d_out;

    unsigned short* xb = (unsigned short*)d_ws;                  // 32 MB
    unsigned short* wt = xb + (size_t)MDIM * KDIM;               // 32 MB

    cvt_x_bf16<<<(MDIM * KDIM / 8) / 256, 256, 0, stream>>>(x, xb);
    gen_Wt<<<(NDIM * KDIM / 8) / 256, 256, 0, stream>>>(wt);

    dim3 grid(NDIM / 256, MDIM / 256);
    gemm_bt<<<grid, 512, 0, stream>>>(xb, wt, out);
}

// Round 9
// 64.362 us; speedup vs baseline: 3.7232x; 3.7232x over previous
//
#include <hip/hip_runtime.h>
#include <hip/hip_bf16.h>

// IDST (DST-III, x2) via the reference's own O(N log N) path, in ONE kernel:
//   y_k = 2*Im{ t_k * S_k },  S = IFFT_8192(b) (unnormalized, sign +),
//   b_n = a_n * x_n * e_n (n<4096; zero-padded), e from expk input,
//   t_k = e_k^2 * e_1.
// Four-step FFT, 8192 = 32 x 32 x 8, one row per 256-thread block:
//   S1: thread c: DFT-32 over n1 of b[256*n1+c] (n1>=16 are zeros),
//       twiddle w8192^(c*k1), write Y[k1][c] to LDS (stride 257: bank-clean).
//   S2: thread (k1,c2): DFT-32 over c1 of Y[k1][8*c1+c2],
//       twiddle w256^(c2*m1), write W at [k1 + 32*(m1*8+c2)] (bank-clean).
//   S3: thread (k1, m1=4*(j>>5)+q): direct DFT-8 over c2, only m2<4 needed;
//       y[k1+32*m1+1024*m2] = 2*Im(t_k * S).  All FFT indices compile-time.
// f32 end-to-end (absmax ~1e-3 vs bf16-GEMM's 2.0). No workspace.

#define NN 4096

__device__ static constexpr float TW32R[16] = {
    1.0f, 0.98078528f, 0.92387953f, 0.83146961f,
    0.70710678f, 0.55557023f, 0.38268343f, 0.19509032f,
    0.0f, -0.19509032f, -0.38268343f, -0.55557023f,
    -0.70710678f, -0.83146961f, -0.92387953f, -0.98078528f};
__device__ static constexpr float TW32I[16] = {
    0.0f, 0.19509032f, 0.38268343f, 0.55557023f,
    0.70710678f, 0.83146961f, 0.92387953f, 0.98078528f,
    1.0f, 0.98078528f, 0.92387953f, 0.83146961f,
    0.70710678f, 0.55557023f, 0.38268343f, 0.19509032f};
// w8^t = exp(+j*2*pi*t/8)
__device__ static constexpr float W8R[8] = {
    1.0f, 0.70710678f, 0.0f, -0.70710678f, -1.0f, -0.70710678f, 0.0f, 0.70710678f};
__device__ static constexpr float W8I[8] = {
    0.0f, 0.70710678f, 1.0f, 0.70710678f, 0.0f, -0.70710678f, -1.0f, -0.70710678f};

__device__ __forceinline__ constexpr int brev5(int x) {
    return ((x & 1) << 4) | ((x & 2) << 2) | (x & 4) | ((x & 8) >> 2) | ((x & 16) >> 4);
}

// In-register 32-point DFT, sign +1 (inverse-FFT kernel), DIF.
// Output: X[k] sits at a[brev5(k)].
__device__ __forceinline__ void fft32(float (&re)[32], float (&im)[32]) {
#pragma unroll
    for (int len = 32; len >= 2; len >>= 1) {
        const int half = len >> 1;
#pragma unroll
        for (int base = 0; base < 32; base += len) {
#pragma unroll
            for (int o = 0; o < half; ++o) {
                const int tw = o * (32 / len);
                float ur = re[base + o], ui = im[base + o];
                float vr = re[base + o + half], vi = im[base + o + half];
                re[base + o] = ur + vr;
                im[base + o] = ui + vi;
                float dr = ur - vr, di = ui - vi;
                re[base + o + half] = dr * TW32R[tw] - di * TW32I[tw];
                im[base + o + half] = dr * TW32I[tw] + di * TW32R[tw];
            }
        }
    }
}

__global__ __launch_bounds__(256) void idst_fft(const float* __restrict__ x,
                                                const float2* __restrict__ expk,
                                                float* __restrict__ y) {
    __shared__ float LRE[8224];   // stage1: [k1*257 + c]; stage2: [k1 + 32*(m1*8+c2)]
    __shared__ float LIM[8224];

    const int j = threadIdx.x;
    const int row = blockIdx.x;
    const float* xr = x + (size_t)row * NN;

    float cre[32], cim[32];

    // ---- Stage 1: b_n = a_n*x_n*e_n at n = 256*i + j (i>=16 -> zero pad) ----
#pragma unroll
    for (int i = 0; i < 16; ++i) {
        int n = j + 256 * i;
        float v = xr[n];
        if (n == NN - 1) v *= 0.5f;
        float2 e = expk[n];               // e_n = e.x + j*(-e.y)
        cre[i] = v * e.x;
        cim[i] = -v * e.y;
    }
#pragma unroll
    for (int i = 16; i < 32; ++i) { cre[i] = 0.0f; cim[i] = 0.0f; }

    fft32(cre, cim);

    // twiddle w8192^(j*k1), iterative rotation; write Y[k1][j]
    {
        float ss, sc;
        __sincosf((float)j * 7.66990393943e-4f, &ss, &sc);   // 2*pi/8192
        float tr = 1.0f, ti = 0.0f;
#pragma unroll
        for (int k1 = 0; k1 < 32; ++k1) {
            const int s = brev5(k1);
            LRE[k1 * 257 + j] = cre[s] * tr - cim[s] * ti;
            LIM[k1 * 257 + j] = cre[s] * ti + cim[s] * tr;
            float nr = tr * sc - ti * ss;
            ti = tr * ss + ti * sc;
            tr = nr;
        }
    }
    __syncthreads();

    // ---- Stage 2: (k1, c2) does DFT-32 over c1 of Y[k1][8*c1 + c2] ----
    const int k1 = j & 31;
    const int c2 = j >> 5;
#pragma unroll
    for (int c1 = 0; c1 < 32; ++c1) {
        cre[c1] = LRE[k1 * 257 + 8 * c1 + c2];
        cim[c1] = LIM[k1 * 257 + 8 * c1 + c2];
    }
    __syncthreads();   // all reads done before overwriting the buffer

    fft32(cre, cim);

    {
        float ss, sc;
        __sincosf((float)c2 * 2.45436926062e-2f, &ss, &sc);  // 2*pi/256
        float tr = 1.0f, ti = 0.0f;
#pragma unroll
        for (int m1 = 0; m1 < 32; ++m1) {
            const int s = brev5(m1);
            LRE[k1 + 32 * (m1 * 8 + c2)] = cre[s] * tr - cim[s] * ti;
            LIM[k1 + 32 * (m1 * 8 + c2)] = cre[s] * ti + cim[s] * tr;
            float nr = tr * sc - ti * ss;
            ti = tr * ss + ti * sc;
            tr = nr;
        }
    }
    __syncthreads();

    // ---- Stage 3: direct DFT-8 over c2 (only m2<4 needed) + epilogue ----
    const float2 e1 = expk[1];
    const float e1r = e1.x, e1i = -e1.y;
    float* yr = y + (size_t)row * NN;

#pragma unroll
    for (int q = 0; q < 4; ++q) {
        const int m1 = (j >> 5) * 4 + q;
        float wre[8], wim[8];
#pragma unroll
        for (int c = 0; c < 8; ++c) {
            wre[c] = LRE[k1 + 32 * (m1 * 8 + c)];
            wim[c] = LIM[k1 + 32 * (m1 * 8 + c)];
        }
#pragma unroll
        for (int m2 = 0; m2 < 4; ++m2) {
            float sr = 0.0f, si = 0.0f;
#pragma unroll
            for (int c = 0; c < 8; ++c) {
                const int t8 = (c * m2) & 7;
                sr += wre[c] * W8R[t8] - wim[c] * W8I[t8];
                si += wre[c] * W8I[t8] + wim[c] * W8R[t8];
            }
            const int k = k1 + 32 * m1 + 1024 * m2;
            float2 ek = expk[k];
            const float er = ek.x, ei = -ek.y;      // e_k
            const float t2r = er * er - ei * ei;    // e_k^2
            const float t2i = 2.0f * er * ei;
            const float tkr = t2r * e1r - t2i * e1i;   // t_k = e_k^2 * e_1
            const float tki = t2r * e1i + t2i * e1r;
            yr[k] = 2.0f * (tkr * si + tki * sr);      // 2*Im(t_k * S_k)
        }
    }
}

extern "C" void kernel_launch(void* const* d_in, const int* in_sizes, int n_in,
                              void* d_out, int out_size, void* d_ws, size_t ws_size,
                              hipStream_t stream) {
    const float*  x    = (const float*)d_in[0];
    const float2* expk = (const float2*)d_in[1];
    float* out = (float*)d_out;

    idst_fft<<<NN, 256, 0, stream>>>(x, expk, out);
}